// Round 1
// baseline (656.979 us; speedup 1.0000x reference)
//
#include <hip/hip_runtime.h>

#define LRELU(a) ((a) > 0.f ? (a) : 0.2f * (a))

// ---------- block-wide inclusive scan helper (256 threads, 4 waves) ----------
__device__ __forceinline__ int blockScanIncl256(int v, int* wl) {
  int t = threadIdx.x, lane = t & 63, w = t >> 6;
  int x = v;
#pragma unroll
  for (int o = 1; o < 64; o <<= 1) {
    int tmp = __shfl_up(x, (unsigned)o, 64);
    if (lane >= o) x += tmp;
  }
  if (lane == 63) wl[w] = x;
  __syncthreads();
  if (t == 0) {
    int s = 0;
#pragma unroll
    for (int j = 0; j < 4; ++j) { int tv = wl[j]; wl[j] = s; s += tv; }
  }
  __syncthreads();
  return x + wl[w];
}

// ---------- CSR build ----------
__global__ __launch_bounds__(256) void k_deg(const int* __restrict__ dst,
                                             int* __restrict__ deg, int E) {
  int e = blockIdx.x * 256 + threadIdx.x;
  if (e < E) atomicAdd(&deg[dst[e]], 1);
}

__global__ __launch_bounds__(256) void k_chunksum(const int* __restrict__ deg,
                                                  int* __restrict__ bsum, int n) {
  __shared__ int wl[4];
  int i = blockIdx.x * 256 + threadIdx.x;
  int v = (i < n) ? deg[i] : 0;
#pragma unroll
  for (int o = 1; o < 64; o <<= 1) v += __shfl_xor(v, o, 64);
  int lane = threadIdx.x & 63, w = threadIdx.x >> 6;
  if (lane == 0) wl[w] = v;
  __syncthreads();
  if (threadIdx.x == 0) bsum[blockIdx.x] = wl[0] + wl[1] + wl[2] + wl[3];
}

// single block; requires nb <= 256 (N <= 65536)
__global__ __launch_bounds__(256) void k_bscan(int* __restrict__ bsum, int nb,
                                               int* __restrict__ csr_off, int n) {
  __shared__ int wl[4];
  int t = threadIdx.x;
  int v = (t < nb) ? bsum[t] : 0;
  int incl = blockScanIncl256(v, wl);
  if (t < nb) bsum[t] = incl - v;  // exclusive block offsets
  if (t == 255) csr_off[n] = incl; // grand total
}

__global__ __launch_bounds__(256) void k_chunkscan(const int* __restrict__ deg,
                                                   const int* __restrict__ bsum,
                                                   int* __restrict__ csr_off,
                                                   int* __restrict__ fill, int n) {
  __shared__ int wl[4];
  int i = blockIdx.x * 256 + threadIdx.x;
  int v = (i < n) ? deg[i] : 0;
  int incl = blockScanIncl256(v, wl);
  int o = bsum[blockIdx.x] + incl - v;
  if (i < n) { csr_off[i] = o; fill[i] = o; }
}

__global__ __launch_bounds__(256) void k_scatter(const int* __restrict__ dst,
                                                 int* __restrict__ fill,
                                                 int* __restrict__ csr_edges, int E) {
  int e = blockIdx.x * 256 + threadIdx.x;
  if (e < E) {
    int p = atomicAdd(&fill[dst[e]], 1);
    csr_edges[p] = e;
  }
}

// ---------- self-loop edge attr = mean of incoming edge attrs ----------
__global__ __launch_bounds__(256) void k_loopattr(const int* __restrict__ csr_off,
                                                  const int* __restrict__ csr_edges,
                                                  const float* __restrict__ edge_attr,
                                                  float* __restrict__ loop_attr, int n) {
  int idx = blockIdx.x * 256 + threadIdx.x;
  int node = idx >> 4, k = idx & 15;
  if (node >= n) return;
  int s = csr_off[node], e = csr_off[node + 1];
  float acc = 0.f;
  for (int i = s; i < e; ++i) acc += edge_attr[csr_edges[i] * 16 + k];
  loop_attr[node * 16 + k] = acc / fmaxf((float)(e - s), 1.f);
}

// ---------- layer 1: h1 = x @ W1 ([N,128]@[128,64]); al_s/al_d per 4 heads ----------
__global__ __launch_bounds__(256) void k_lin1(const float* __restrict__ x,
                                              const float* __restrict__ W1,
                                              const float* __restrict__ as1,
                                              const float* __restrict__ ad1,
                                              float* __restrict__ h1,
                                              float* __restrict__ als,
                                              float* __restrict__ ald, int n) {
  __shared__ float Wl[128 * 64];  // 32 KB
  __shared__ float xl[4][128];
  int t = threadIdx.x;
  for (int i = t; i < 128 * 64; i += 256) Wl[i] = W1[i];
  for (int i = t; i < 4 * 128; i += 256) {
    int nn = blockIdx.x * 4 + (i >> 7);
    xl[i >> 7][i & 127] = (nn < n) ? x[nn * 128 + (i & 127)] : 0.f;
  }
  __syncthreads();
  int w = t >> 6, lane = t & 63;
  int node = blockIdx.x * 4 + w;
  if (node >= n) return;
  float acc = 0.f;
#pragma unroll 16
  for (int k = 0; k < 128; ++k) acc = fmaf(xl[w][k], Wl[k * 64 + lane], acc);
  h1[node * 64 + lane] = acc;
  float ps = acc * as1[lane];  // as1 flat [h*16+c]
  float pd = acc * ad1[lane];
#pragma unroll
  for (int o = 1; o < 16; o <<= 1) {
    ps += __shfl_xor(ps, o, 64);
    pd += __shfl_xor(pd, o, 64);
  }
  if ((lane & 15) == 0) {
    als[node * 4 + (lane >> 4)] = ps;
    ald[node * 4 + (lane >> 4)] = pd;
  }
}

// ---------- layer 1 edge logits: ale[e,h] = edge_attr[e,:] @ (We1 x ae1)[:,h] ----------
__global__ __launch_bounds__(256) void k_ale1(const float* __restrict__ edge_attr,
                                              const float* __restrict__ loop_attr,
                                              const float* __restrict__ We1,
                                              const float* __restrict__ ae1,
                                              float* __restrict__ ale,
                                              float* __restrict__ aleL, int E, int n) {
  __shared__ float wa[64];  // [k*4+h]
  int t = threadIdx.x;
  if (t < 64) {
    int k = t >> 2, h = t & 3;
    float s = 0.f;
#pragma unroll
    for (int c = 0; c < 16; ++c) s = fmaf(We1[k * 64 + h * 16 + c], ae1[h * 16 + c], s);
    wa[t] = s;
  }
  __syncthreads();
  int idx = blockIdx.x * 256 + t;
  if (idx >= E + n) return;
  const float* ea = (idx < E) ? (edge_attr + (size_t)idx * 16)
                              : (loop_attr + (size_t)(idx - E) * 16);
  float a0 = 0.f, a1 = 0.f, a2 = 0.f, a3 = 0.f;
#pragma unroll
  for (int k = 0; k < 16; ++k) {
    float v = ea[k];
    a0 = fmaf(v, wa[k * 4 + 0], a0);
    a1 = fmaf(v, wa[k * 4 + 1], a1);
    a2 = fmaf(v, wa[k * 4 + 2], a2);
    a3 = fmaf(v, wa[k * 4 + 3], a3);
  }
  float* o = (idx < E) ? (ale + (size_t)idx * 4) : (aleL + (size_t)(idx - E) * 4);
  o[0] = a0; o[1] = a1; o[2] = a2; o[3] = a3;
}

// ---------- layer 1 aggregation: one wave per node, lanes = 64 channels ----------
__global__ __launch_bounds__(256) void k_agg1(const int* __restrict__ csr_off,
                                              const int* __restrict__ csr_edges,
                                              const int* __restrict__ src,
                                              const float* __restrict__ als,
                                              const float* __restrict__ ald,
                                              const float* __restrict__ ale,
                                              const float* __restrict__ aleL,
                                              const float* __restrict__ h1,
                                              const float* __restrict__ b1,
                                              float* __restrict__ out1, int n) {
  int t = threadIdx.x, w = t >> 6, lane = t & 63;
  int node = blockIdx.x * 4 + w;
  if (node >= n) return;
  int head = lane >> 4;
  int s0 = csr_off[node], s1 = csr_off[node + 1];
  float ad = ald[node * 4 + head];
  float al = als[node * 4 + head] + ad + aleL[node * 4 + head];  // self-loop logit
  al = LRELU(al);
  float mx = al;
  for (int i = s0; i < s1; ++i) {
    int e = csr_edges[i];
    int s = src[e];
    float a = als[s * 4 + head] + ad + ale[e * 4 + head];
    a = LRELU(a);
    mx = fmaxf(mx, a);
  }
  float den = expf(al - mx);  // self-loop numerator
  float acc = den * h1[node * 64 + lane];
  for (int i = s0; i < s1; ++i) {
    int e = csr_edges[i];
    int s = src[e];
    float a = als[s * 4 + head] + ad + ale[e * 4 + head];
    a = LRELU(a);
    float ex = expf(a - mx);
    den += ex;
    acc = fmaf(ex, h1[s * 64 + lane], acc);
  }
  float r = acc / den + b1[lane];
  out1[node * 64 + lane] = r > 0.f ? r : expm1f(r);  // ELU fused
}

// ---------- layer 2: h2 = out1 @ W2 ([N,64]@[64,64]); scalar al_s/al_d ----------
__global__ __launch_bounds__(256) void k_lin2(const float* __restrict__ xin,
                                              const float* __restrict__ W2,
                                              const float* __restrict__ as2,
                                              const float* __restrict__ ad2,
                                              float* __restrict__ h2,
                                              float* __restrict__ als,
                                              float* __restrict__ ald, int n) {
  __shared__ float Wl[64 * 64];  // 16 KB
  __shared__ float xl[4][64];
  int t = threadIdx.x;
  for (int i = t; i < 64 * 64; i += 256) Wl[i] = W2[i];
  {
    int nn = blockIdx.x * 4 + (t >> 6);
    xl[t >> 6][t & 63] = (nn < n) ? xin[nn * 64 + (t & 63)] : 0.f;
  }
  __syncthreads();
  int w = t >> 6, lane = t & 63;
  int node = blockIdx.x * 4 + w;
  if (node >= n) return;
  float acc = 0.f;
#pragma unroll 16
  for (int k = 0; k < 64; ++k) acc = fmaf(xl[w][k], Wl[k * 64 + lane], acc);
  h2[node * 64 + lane] = acc;
  float ps = acc * as2[lane];
  float pd = acc * ad2[lane];
#pragma unroll
  for (int o = 1; o < 64; o <<= 1) {
    ps += __shfl_xor(ps, o, 64);
    pd += __shfl_xor(pd, o, 64);
  }
  if (lane == 0) { als[node] = ps; ald[node] = pd; }
}

__global__ __launch_bounds__(256) void k_ale2(const float* __restrict__ edge_attr,
                                              const float* __restrict__ loop_attr,
                                              const float* __restrict__ We2,
                                              const float* __restrict__ ae2,
                                              float* __restrict__ ale,
                                              float* __restrict__ aleL, int E, int n) {
  __shared__ float wa[16];
  int t = threadIdx.x;
  if (t < 16) {
    float s = 0.f;
#pragma unroll
    for (int c = 0; c < 64; ++c) s = fmaf(We2[t * 64 + c], ae2[c], s);
    wa[t] = s;
  }
  __syncthreads();
  int idx = blockIdx.x * 256 + t;
  if (idx >= E + n) return;
  const float* ea = (idx < E) ? (edge_attr + (size_t)idx * 16)
                              : (loop_attr + (size_t)(idx - E) * 16);
  float a = 0.f;
#pragma unroll
  for (int k = 0; k < 16; ++k) a = fmaf(ea[k], wa[k], a);
  if (idx < E) ale[idx] = a;
  else aleL[idx - E] = a;
}

__global__ __launch_bounds__(256) void k_agg2(const int* __restrict__ csr_off,
                                              const int* __restrict__ csr_edges,
                                              const int* __restrict__ src,
                                              const float* __restrict__ als,
                                              const float* __restrict__ ald,
                                              const float* __restrict__ ale,
                                              const float* __restrict__ aleL,
                                              const float* __restrict__ h2,
                                              const float* __restrict__ b2,
                                              float* __restrict__ out2, int n) {
  int t = threadIdx.x, w = t >> 6, lane = t & 63;
  int node = blockIdx.x * 4 + w;
  if (node >= n) return;
  int s0 = csr_off[node], s1 = csr_off[node + 1];
  float ad = ald[node];
  float al = als[node] + ad + aleL[node];
  al = LRELU(al);
  float mx = al;
  for (int i = s0; i < s1; ++i) {
    int e = csr_edges[i];
    int s = src[e];
    float a = als[s] + ad + ale[e];
    a = LRELU(a);
    mx = fmaxf(mx, a);
  }
  float den = expf(al - mx);
  float acc = den * h2[node * 64 + lane];
  for (int i = s0; i < s1; ++i) {
    int e = csr_edges[i];
    int s = src[e];
    float a = als[s] + ad + ale[e];
    a = LRELU(a);
    float ex = expf(a - mx);
    den += ex;
    acc = fmaf(ex, h2[s * 64 + lane], acc);
  }
  out2[node * 64 + lane] = acc / den + b2[lane];  // H2=1: mean over heads = identity
}

// ---------- pooling: sorted batch, wave handles 64 consecutive nodes ----------
__global__ __launch_bounds__(256) void k_pool(const float* __restrict__ out2,
                                              const int* __restrict__ batch,
                                              float* __restrict__ pooled,
                                              float* __restrict__ cnt, int n) {
  int wgl = blockIdx.x * 4 + (threadIdx.x >> 6);
  int lane = threadIdx.x & 63;
  int i0 = wgl * 64;
  if (i0 >= n) return;
  int i1 = min(i0 + 64, n);
  int cur = -1;
  float acc = 0.f, c = 0.f;
  for (int i = i0; i < i1; ++i) {
    int g = batch[i];
    if (g != cur) {
      if (cur >= 0) {
        atomicAdd(&pooled[cur * 64 + lane], acc);
        if (lane == 0) atomicAdd(&cnt[cur], c);
      }
      cur = g; acc = 0.f; c = 0.f;
    }
    acc += out2[i * 64 + lane];
    c += 1.f;
  }
  if (cur >= 0) {
    atomicAdd(&pooled[cur * 64 + lane], acc);
    if (lane == 0) atomicAdd(&cnt[cur], c);
  }
}

// ---------- final: out[g,:] = (pooled[g,:]/cnt[g]) @ Pw + Pb ----------
__global__ __launch_bounds__(64) void k_final(const float* __restrict__ pooled,
                                              const float* __restrict__ cnt,
                                              const float* __restrict__ Pw,
                                              const float* __restrict__ Pb,
                                              float* __restrict__ out) {
  __shared__ float m[64];
  int g = blockIdx.x, o = threadIdx.x;
  m[o] = pooled[g * 64 + o] / fmaxf(cnt[g], 1.f);
  __syncthreads();
  float s = Pb[o];
#pragma unroll
  for (int c = 0; c < 64; ++c) s = fmaf(m[c], Pw[c * 64 + o], s);
  out[g * 64 + o] = s;
}

extern "C" void kernel_launch(void* const* d_in, const int* in_sizes, int n_in,
                              void* d_out, int out_size, void* d_ws, size_t ws_size,
                              hipStream_t stream) {
  const float* x         = (const float*)d_in[0];
  const int*   edge_index= (const int*)d_in[1];
  const float* edge_attr = (const float*)d_in[2];
  const int*   batch     = (const int*)d_in[3];
  const float* W1  = (const float*)d_in[4];
  const float* as1 = (const float*)d_in[5];
  const float* ad1 = (const float*)d_in[6];
  const float* We1 = (const float*)d_in[7];
  const float* ae1 = (const float*)d_in[8];
  const float* b1  = (const float*)d_in[9];
  const float* W2  = (const float*)d_in[10];
  const float* as2 = (const float*)d_in[11];
  const float* ad2 = (const float*)d_in[12];
  const float* We2 = (const float*)d_in[13];
  const float* ae2 = (const float*)d_in[14];
  const float* b2  = (const float*)d_in[15];
  const float* Pw  = (const float*)d_in[16];
  const float* Pb  = (const float*)d_in[17];

  const int N = in_sizes[0] / 128;
  const int E = in_sizes[1] / 2;
  const int G = out_size / 64;
  const int* srcI = edge_index;
  const int* dstI = edge_index + E;

  // ---- workspace layout (16B-aligned slots); total ~48 MB ----
  float* ws = (float*)d_ws;
  size_t off = 0;
  auto alloc = [&](size_t elems) {
    float* p = ws + off;
    off += (elems + 3) & ~(size_t)3;
    return p;
  };
  int*   deg       = (int*)alloc(N);            // zeroed
  float* cnt       = alloc(G);                  // zeroed
  float* pooled    = alloc((size_t)G * 64);     // zeroed
  size_t zero_bytes = off * sizeof(float);
  int*   csr_off   = (int*)alloc(N + 1);
  int*   fill      = (int*)alloc(N);
  int*   csr_edges = (int*)alloc(E);
  int*   bsum      = (int*)alloc(1024);
  float* loop_attr = alloc((size_t)N * 16);
  float* h         = alloc((size_t)N * 64);     // h1, reused as h2
  float* als       = alloc((size_t)N * 4);      // layer2 reuses first N
  float* ald       = alloc((size_t)N * 4);
  float* ale       = alloc((size_t)E * 4);      // layer2 reuses first E
  float* aleL      = alloc((size_t)N * 4);      // layer2 reuses first N
  float* outn      = alloc((size_t)N * 64);     // out1, reused as out2

  (void)ws_size; (void)n_in;
  hipMemsetAsync(d_ws, 0, zero_bytes, stream);

  const int ebl  = (E + 255) / 256;
  const int nb   = (N + 255) / 256;
  const int nbl4 = (N + 3) / 4;
  const int eN   = (E + N + 255) / 256;

  // CSR build (by dst)
  k_deg<<<ebl, 256, 0, stream>>>(dstI, deg, E);
  k_chunksum<<<nb, 256, 0, stream>>>(deg, bsum, N);
  k_bscan<<<1, 256, 0, stream>>>(bsum, nb, csr_off, N);
  k_chunkscan<<<nb, 256, 0, stream>>>(deg, bsum, csr_off, fill, N);
  k_scatter<<<ebl, 256, 0, stream>>>(dstI, fill, csr_edges, E);
  k_loopattr<<<(N * 16 + 255) / 256, 256, 0, stream>>>(csr_off, csr_edges, edge_attr,
                                                       loop_attr, N);

  // layer 1
  k_lin1<<<nbl4, 256, 0, stream>>>(x, W1, as1, ad1, h, als, ald, N);
  k_ale1<<<eN, 256, 0, stream>>>(edge_attr, loop_attr, We1, ae1, ale, aleL, E, N);
  k_agg1<<<nbl4, 256, 0, stream>>>(csr_off, csr_edges, srcI, als, ald, ale, aleL, h,
                                   b1, outn, N);

  // layer 2 (reuses h/als/ald/ale/aleL slots; out2 overwrites out1)
  k_lin2<<<nbl4, 256, 0, stream>>>(outn, W2, as2, ad2, h, als, ald, N);
  k_ale2<<<eN, 256, 0, stream>>>(edge_attr, loop_attr, We2, ae2, ale, aleL, E, N);
  k_agg2<<<nbl4, 256, 0, stream>>>(csr_off, csr_edges, srcI, als, ald, ale, aleL, h,
                                   b2, outn, N);

  // pool + project
  k_pool<<<((N + 63) / 64 + 3) / 4, 256, 0, stream>>>(outn, batch, pooled, cnt, N);
  k_final<<<G, 64, 0, stream>>>(pooled, cnt, Pw, Pb, (float*)d_out);
}